// Round 1
// baseline (1875.242 us; speedup 1.0000x reference)
//
#include <hip/hip_runtime.h>

// Fused TemporalAttentionLayer for MI355X (gfx950), round 3.
// N=4096 nodes, T=64, D=256, H=16, dh=16. One node per block, 4 waves.
// Wave w owns output columns [64w, 64w+64) == heads 4w..4w+3.
//
// Round-3 structure (occupancy push):
//  - Per-HEAD processing: Q,K,V GEMMs fused into ONE ks-loop per head
//    (shared h-fragments), then attention for that head, packed O held in
//    regs. Peak register pressure ~110 -> __launch_bounds__(256,4) ->
//    4 blocks/CU (was 2).
//  - Causal tile skip: 16x16 score tiles with js>i are fully masked ->
//    skipped. 20 instead of 32 attention MFMAs per head.
//  - exp2 with folded scale + v_rcp for softmax normalize.
// Layouts identical to round 2 (all transposes via operand-swapped MFMA).

typedef __attribute__((ext_vector_type(4))) float f32x4;
typedef __attribute__((ext_vector_type(8))) short bf16x8;
typedef __attribute__((ext_vector_type(4))) short bf16x4;

__device__ __forceinline__ unsigned short f2b(float f) {
    union { float f; unsigned u; } v; v.f = f;
    unsigned r = v.u + 0x7fffu + ((v.u >> 16) & 1u);   // RNE
    return (unsigned short)(r >> 16);
}
__device__ __forceinline__ float b2f(unsigned short s) {
    union { unsigned u; float f; } v; v.u = ((unsigned)s) << 16; return v.f;
}

// ---- preprocess: cast fp32 weights [K=256][N=256] to bf16 in MFMA frag order.
// Layout: [ntile(16)][kstep(8)][lane(64)][j(8)],
// element = W[ks*32+(lane>>4)*8+j][nt*16+(lane&15)].
// Serves as B-frag of W (straight GEMM) AND A-frag of W^T (transposed GEMM).
__global__ void swizzle_w_kernel(const float* __restrict__ Wq,
                                 const float* __restrict__ Wk,
                                 const float* __restrict__ Wv,
                                 const float* __restrict__ Wf,
                                 unsigned short* __restrict__ ws) {
    int tid  = blockIdx.x * 256 + threadIdx.x;   // 0..32767
    int mat  = tid >> 13;
    int rem  = tid & 8191;
    int nt   = rem >> 9;
    int ks   = (rem >> 6) & 7;
    int lane = rem & 63;
    const float* W = (mat == 0) ? Wq : (mat == 1) ? Wk : (mat == 2) ? Wv : Wf;
    int n  = nt * 16 + (lane & 15);
    int k0 = ks * 32 + (lane >> 4) * 8;
    bf16x8 o;
#pragma unroll
    for (int j = 0; j < 8; ++j) o[j] = (short)f2b(W[(k0 + j) * 256 + n]);
    *(bf16x8*)(ws + (size_t)mat * 65536 + (size_t)rem * 8) = o;
}

__global__ __launch_bounds__(256, 4) void fused_node_kernel(
    const float* __restrict__ x, const float* __restrict__ pos,
    const unsigned short* __restrict__ wsw, const float* __restrict__ bff,
    float* __restrict__ out)
{
    __shared__ unsigned short lds_h[64 * 264];   // h, later attn_out (bf16, pad 8)

    const int tid  = threadIdx.x;
    const int w    = tid >> 6;
    const int lane = tid & 63;
    const int quad = lane >> 4;
    const int lc   = lane & 15;
    const int node = blockIdx.x;

    // ---- stage 1: h = x + pos_emb  -> bf16 LDS
    {
        const float4* xv = (const float4*)(x + (size_t)node * 16384);
        const float4* pv = (const float4*)pos;
#pragma unroll
        for (int it = 0; it < 16; ++it) {
            int idx = it * 256 + tid;           // 4096 float4 chunks
            float4 a = xv[idx];
            float4 b = pv[idx];
            int row = idx >> 6, c4 = idx & 63;
            ushort4 o;
            o.x = f2b(a.x + b.x); o.y = f2b(a.y + b.y);
            o.z = f2b(a.z + b.z); o.w = f2b(a.w + b.w);
            *(ushort4*)&lds_h[row * 264 + c4 * 4] = o;
        }
    }
    __syncthreads();

    const f32x4 fzero = {0.f, 0.f, 0.f, 0.f};

    // fragment base pointers for this wave (ntile chunk = w*4 .. w*4+3)
    const unsigned short* wq_b = wsw;
    const unsigned short* wk_b = wsw + 65536;
    const unsigned short* wv_b = wsw + 131072;
    const unsigned short* wf_b = wsw + 196608;
#define WFRAG(base, mt, ks) (*(const bf16x8*)((base) + (size_t)(((w * 4 + (mt)) * 8 + (ks)) * 64 + lane) * 8))
#define HFRAG(j, ks) (*(const bf16x8*)&lds_h[(16 * (j) + lc) * 264 + (ks) * 32 + quad * 8])

    // exp(s*0.125) == exp2(s * 0.125*log2(e))
    const float SC = 0.18033688011112042f;

    bf16x4 o_pk[4][4];   // packed attn_out [head][ttile], held across head loop

#pragma unroll
    for (int h = 0; h < 4; ++h) {
        // ---- fused Q^T / K^T / V GEMM for head (4w+h), one pass over ks.
        // aq[j]: lane holds Q[t=16j+lc][dh=4quad+r]   (score A/B frag)
        // ak[j]: lane holds K[t=16j+lc][dh=4quad+r]
        // av[i]: lane holds V[s=16i+4quad+r][dh=lc]   (PV B frag)
        f32x4 aq[4], ak[4], av[4];
#pragma unroll
        for (int j = 0; j < 4; ++j) { aq[j] = fzero; ak[j] = fzero; av[j] = fzero; }
#pragma unroll
        for (int ks = 0; ks < 8; ++ks) {
            bf16x8 hf[4];
#pragma unroll
            for (int j = 0; j < 4; ++j) hf[j] = HFRAG(j, ks);
            bf16x8 wfq = WFRAG(wq_b, h, ks);
            bf16x8 wfk = WFRAG(wk_b, h, ks);
            bf16x8 wfv = WFRAG(wv_b, h, ks);
#pragma unroll
            for (int j = 0; j < 4; ++j) {
                aq[j] = __builtin_amdgcn_mfma_f32_16x16x32_bf16(wfq, hf[j], aq[j], 0, 0, 0);
                ak[j] = __builtin_amdgcn_mfma_f32_16x16x32_bf16(wfk, hf[j], ak[j], 0, 0, 0);
                av[j] = __builtin_amdgcn_mfma_f32_16x16x32_bf16(hf[j], wfv, av[j], 0, 0, 0);
            }
        }
        bf16x4 qf[4], kf[4], vf[4];
#pragma unroll
        for (int j = 0; j < 4; ++j)
#pragma unroll
            for (int r = 0; r < 4; ++r) {
                qf[j][r] = (short)f2b(aq[j][r]);
                kf[j][r] = (short)f2b(ak[j][r]);
                vf[j][r] = (short)f2b(av[j][r]);
            }

        // ---- attention for this head, row-block (ttile) at a time.
        // Causal skip: score tile (i,js) is fully masked when js>i; fully
        // unmasked when js<i; diagonal js==i needs the elementwise mask.
#pragma unroll
        for (int i = 0; i < 4; ++i) {
            f32x4 st[4];   // only st[0..i] used
#pragma unroll
            for (int js = 0; js <= i; ++js)
                st[js] = __builtin_amdgcn_mfma_f32_16x16x16bf16_1k(kf[js], qf[i], fzero, 0, 0, 0);
            // lane holds S[t=16i+lc][s=16js+4quad+r]
            float sum = 0.f;
#pragma unroll
            for (int js = 0; js <= i; ++js)
#pragma unroll
                for (int r = 0; r < 4; ++r) {
                    float p = __builtin_amdgcn_exp2f(st[js][r] * SC);
                    if (js == i) p = (4 * quad + r <= lc) ? p : 0.0f;
                    st[js][r] = p;
                    sum += p;
                }
            sum += __shfl_xor(sum, 16, 64);
            sum += __shfl_xor(sum, 32, 64);
            float rinv = __builtin_amdgcn_rcpf(sum);

            f32x4 O = fzero;
#pragma unroll
            for (int js = 0; js <= i; ++js) {
                bf16x4 pa;
#pragma unroll
                for (int r = 0; r < 4; ++r) pa[r] = (short)f2b(st[js][r] * rinv);
                O = __builtin_amdgcn_mfma_f32_16x16x16bf16_1k(pa, vf[js], O, 0, 0, 0);
            }
            // O lane holds attn_out[t=16i+4quad+r][dh=lc]
#pragma unroll
            for (int r = 0; r < 4; ++r) o_pk[h][i][r] = (short)f2b(O[r]);
        }
    }

    __syncthreads();   // all lds_h (h) reads done; it now becomes attn_out

#pragma unroll
    for (int h = 0; h < 4; ++h)
#pragma unroll
        for (int i = 0; i < 4; ++i)
#pragma unroll
            for (int r = 0; r < 4; ++r)
                lds_h[(16 * i + 4 * quad + r) * 264 + w * 64 + h * 16 + lc] =
                    (unsigned short)o_pk[h][i][r];

    __syncthreads();   // attn_out complete across waves

    // ---- FFN (straight): af[i][jn] = attn_out @ Wff
    f32x4 af[4][4];
#pragma unroll
    for (int i = 0; i < 4; ++i)
#pragma unroll
        for (int j = 0; j < 4; ++j) af[i][j] = fzero;
#pragma unroll
    for (int ks = 0; ks < 8; ++ks) {
        bf16x8 hf[4];
#pragma unroll
        for (int i = 0; i < 4; ++i) hf[i] = HFRAG(i, ks);
#pragma unroll
        for (int jn = 0; jn < 4; ++jn) {
            bf16x8 wff = WFRAG(wf_b, jn, ks);
#pragma unroll
            for (int i = 0; i < 4; ++i)
                af[i][jn] = __builtin_amdgcn_mfma_f32_16x16x32_bf16(hf[i], wff, af[i][jn], 0, 0, 0);
        }
    }
    {
        float bias[4];
#pragma unroll
        for (int jn = 0; jn < 4; ++jn) bias[jn] = bff[w * 64 + jn * 16 + lc];
        float* outn = out + (size_t)node * 16384;
#pragma unroll
        for (int i = 0; i < 4; ++i)
#pragma unroll
            for (int jn = 0; jn < 4; ++jn)
#pragma unroll
                for (int r = 0; r < 4; ++r) {
                    int row = i * 16 + quad * 4 + r;
                    int col = w * 64 + jn * 16 + lc;
                    float v = af[i][jn][r] + bias[jn];
                    v = fmaxf(v, 0.0f);
                    v += b2f(lds_h[row * 264 + col]);
                    outn[row * 256 + col] = v;
                }
    }
#undef WFRAG
#undef HFRAG
}

extern "C" void kernel_launch(void* const* d_in, const int* in_sizes, int n_in,
                              void* d_out, int out_size, void* d_ws, size_t ws_size,
                              hipStream_t stream) {
    const float* x   = (const float*)d_in[0];
    const float* pos = (const float*)d_in[1];
    const float* Wq  = (const float*)d_in[2];
    const float* Wk  = (const float*)d_in[3];
    const float* Wv  = (const float*)d_in[4];
    const float* Wf  = (const float*)d_in[5];
    const float* bff = (const float*)d_in[6];
    unsigned short* wsw = (unsigned short*)d_ws;   // 4 x 65536 bf16 = 512 KB
    float* o = (float*)d_out;

    hipLaunchKernelGGL(swizzle_w_kernel, dim3(128), dim3(256), 0, stream, Wq, Wk, Wv, Wf, wsw);
    hipLaunchKernelGGL(fused_node_kernel, dim3(4096), dim3(256), 0, stream, x, pos, wsw, bff, o);
}

// Round 2
// 1392.553 us; speedup vs baseline: 1.3466x; 1.3466x over previous
//
#include <hip/hip_runtime.h>

// Fused TemporalAttentionLayer for MI355X (gfx950), round 4.
// N=4096 nodes, T=64, D=256, H=16, dh=16. One node per block, 4 waves.
// Wave w owns output columns [64w, 64w+64) == heads 4w..4w+3.
//
// Round-4 = round-3 structure with the register budget fixed:
//  __launch_bounds__(256, 3): 512/3 ~= 170 total regs/wave -- holds the
//  ~130-reg peak of the per-head fused body WITHOUT spilling (round 3's
//  (256,4) capped at 128 total -> 64 arch + 64 accum -> 5.7 GB scratch
//  spill traffic, 4x regression). 3 blocks/CU, LDS 101 KB/CU.
//
//  - Per-HEAD processing: Q,K,V GEMMs fused into ONE ks-loop per head
//    (shared h-fragments), then attention for that head, packed O held in
//    regs until the h-buffer is dead.
//  - Causal tile skip: 16x16 score tiles with js>i are fully masked ->
//    20 instead of 32 attention MFMAs per head.
//  - exp2 with folded scale + v_rcp for softmax normalize.

typedef __attribute__((ext_vector_type(4))) float f32x4;
typedef __attribute__((ext_vector_type(8))) short bf16x8;
typedef __attribute__((ext_vector_type(4))) short bf16x4;

__device__ __forceinline__ unsigned short f2b(float f) {
    union { float f; unsigned u; } v; v.f = f;
    unsigned r = v.u + 0x7fffu + ((v.u >> 16) & 1u);   // RNE
    return (unsigned short)(r >> 16);
}
__device__ __forceinline__ float b2f(unsigned short s) {
    union { unsigned u; float f; } v; v.u = ((unsigned)s) << 16; return v.f;
}

// ---- preprocess: cast fp32 weights [K=256][N=256] to bf16 in MFMA frag order.
// Layout: [ntile(16)][kstep(8)][lane(64)][j(8)],
// element = W[ks*32+(lane>>4)*8+j][nt*16+(lane&15)].
// Serves as B-frag of W (straight GEMM) AND A-frag of W^T (transposed GEMM).
__global__ void swizzle_w_kernel(const float* __restrict__ Wq,
                                 const float* __restrict__ Wk,
                                 const float* __restrict__ Wv,
                                 const float* __restrict__ Wf,
                                 unsigned short* __restrict__ ws) {
    int tid  = blockIdx.x * 256 + threadIdx.x;   // 0..32767
    int mat  = tid >> 13;
    int rem  = tid & 8191;
    int nt   = rem >> 9;
    int ks   = (rem >> 6) & 7;
    int lane = rem & 63;
    const float* W = (mat == 0) ? Wq : (mat == 1) ? Wk : (mat == 2) ? Wv : Wf;
    int n  = nt * 16 + (lane & 15);
    int k0 = ks * 32 + (lane >> 4) * 8;
    bf16x8 o;
#pragma unroll
    for (int j = 0; j < 8; ++j) o[j] = (short)f2b(W[(k0 + j) * 256 + n]);
    *(bf16x8*)(ws + (size_t)mat * 65536 + (size_t)rem * 8) = o;
}

__global__ __launch_bounds__(256, 3) void fused_node_kernel(
    const float* __restrict__ x, const float* __restrict__ pos,
    const unsigned short* __restrict__ wsw, const float* __restrict__ bff,
    float* __restrict__ out)
{
    __shared__ unsigned short lds_h[64 * 264];   // h, later attn_out (bf16, pad 8)

    const int tid  = threadIdx.x;
    const int w    = tid >> 6;
    const int lane = tid & 63;
    const int quad = lane >> 4;
    const int lc   = lane & 15;
    const int node = blockIdx.x;

    // ---- stage 1: h = x + pos_emb  -> bf16 LDS
    {
        const float4* xv = (const float4*)(x + (size_t)node * 16384);
        const float4* pv = (const float4*)pos;
#pragma unroll
        for (int it = 0; it < 16; ++it) {
            int idx = it * 256 + tid;           // 4096 float4 chunks
            float4 a = xv[idx];
            float4 b = pv[idx];
            int row = idx >> 6, c4 = idx & 63;
            ushort4 o;
            o.x = f2b(a.x + b.x); o.y = f2b(a.y + b.y);
            o.z = f2b(a.z + b.z); o.w = f2b(a.w + b.w);
            *(ushort4*)&lds_h[row * 264 + c4 * 4] = o;
        }
    }
    __syncthreads();

    const f32x4 fzero = {0.f, 0.f, 0.f, 0.f};

    // fragment base pointers for this wave (ntile chunk = w*4 .. w*4+3)
    const unsigned short* wq_b = wsw;
    const unsigned short* wk_b = wsw + 65536;
    const unsigned short* wv_b = wsw + 131072;
    const unsigned short* wf_b = wsw + 196608;
#define WFRAG(base, mt, ks) (*(const bf16x8*)((base) + (size_t)(((w * 4 + (mt)) * 8 + (ks)) * 64 + lane) * 8))
#define HFRAG(j, ks) (*(const bf16x8*)&lds_h[(16 * (j) + lc) * 264 + (ks) * 32 + quad * 8])

    // exp(s*0.125) == exp2(s * 0.125*log2(e))
    const float SC = 0.18033688011112042f;

    bf16x4 o_pk[4][4];   // packed attn_out [head][ttile], held across head loop

#pragma unroll
    for (int h = 0; h < 4; ++h) {
        // ---- fused Q^T / K^T / V GEMM for head (4w+h), one pass over ks.
        // aq[j]: lane holds Q[t=16j+lc][dh=4quad+r]   (score A/B frag)
        // ak[j]: lane holds K[t=16j+lc][dh=4quad+r]
        // av[i]: lane holds V[s=16i+4quad+r][dh=lc]   (PV B frag)
        f32x4 aq[4], ak[4], av[4];
#pragma unroll
        for (int j = 0; j < 4; ++j) { aq[j] = fzero; ak[j] = fzero; av[j] = fzero; }
#pragma unroll
        for (int ks = 0; ks < 8; ++ks) {
            bf16x8 hf[4];
#pragma unroll
            for (int j = 0; j < 4; ++j) hf[j] = HFRAG(j, ks);
            bf16x8 wfq = WFRAG(wq_b, h, ks);
            bf16x8 wfk = WFRAG(wk_b, h, ks);
            bf16x8 wfv = WFRAG(wv_b, h, ks);
#pragma unroll
            for (int j = 0; j < 4; ++j) {
                aq[j] = __builtin_amdgcn_mfma_f32_16x16x32_bf16(wfq, hf[j], aq[j], 0, 0, 0);
                ak[j] = __builtin_amdgcn_mfma_f32_16x16x32_bf16(wfk, hf[j], ak[j], 0, 0, 0);
                av[j] = __builtin_amdgcn_mfma_f32_16x16x32_bf16(hf[j], wfv, av[j], 0, 0, 0);
            }
        }
        bf16x4 qf[4], kf[4], vf[4];
#pragma unroll
        for (int j = 0; j < 4; ++j)
#pragma unroll
            for (int r = 0; r < 4; ++r) {
                qf[j][r] = (short)f2b(aq[j][r]);
                kf[j][r] = (short)f2b(ak[j][r]);
                vf[j][r] = (short)f2b(av[j][r]);
            }

        // ---- attention for this head, row-block (ttile) at a time.
        // Causal skip: score tile (i,js) is fully masked when js>i; fully
        // unmasked when js<i; diagonal js==i needs the elementwise mask.
#pragma unroll
        for (int i = 0; i < 4; ++i) {
            f32x4 st[4];   // only st[0..i] used
#pragma unroll
            for (int js = 0; js <= i; ++js)
                st[js] = __builtin_amdgcn_mfma_f32_16x16x16bf16_1k(kf[js], qf[i], fzero, 0, 0, 0);
            // lane holds S[t=16i+lc][s=16js+4quad+r]
            float sum = 0.f;
#pragma unroll
            for (int js = 0; js <= i; ++js)
#pragma unroll
                for (int r = 0; r < 4; ++r) {
                    float p = __builtin_amdgcn_exp2f(st[js][r] * SC);
                    if (js == i) p = (4 * quad + r <= lc) ? p : 0.0f;
                    st[js][r] = p;
                    sum += p;
                }
            sum += __shfl_xor(sum, 16, 64);
            sum += __shfl_xor(sum, 32, 64);
            float rinv = __builtin_amdgcn_rcpf(sum);

            f32x4 O = fzero;
#pragma unroll
            for (int js = 0; js <= i; ++js) {
                bf16x4 pa;
#pragma unroll
                for (int r = 0; r < 4; ++r) pa[r] = (short)f2b(st[js][r] * rinv);
                O = __builtin_amdgcn_mfma_f32_16x16x16bf16_1k(pa, vf[js], O, 0, 0, 0);
            }
            // O lane holds attn_out[t=16i+4quad+r][dh=lc]
#pragma unroll
            for (int r = 0; r < 4; ++r) o_pk[h][i][r] = (short)f2b(O[r]);
        }
    }

    __syncthreads();   // all lds_h (h) reads done; it now becomes attn_out

#pragma unroll
    for (int h = 0; h < 4; ++h)
#pragma unroll
        for (int i = 0; i < 4; ++i)
#pragma unroll
            for (int r = 0; r < 4; ++r)
                lds_h[(16 * i + 4 * quad + r) * 264 + w * 64 + h * 16 + lc] =
                    (unsigned short)o_pk[h][i][r];

    __syncthreads();   // attn_out complete across waves

    // ---- FFN (straight): af[i][jn] = attn_out @ Wff
    f32x4 af[4][4];
#pragma unroll
    for (int i = 0; i < 4; ++i)
#pragma unroll
        for (int j = 0; j < 4; ++j) af[i][j] = fzero;
#pragma unroll
    for (int ks = 0; ks < 8; ++ks) {
        bf16x8 hf[4];
#pragma unroll
        for (int i = 0; i < 4; ++i) hf[i] = HFRAG(i, ks);
#pragma unroll
        for (int jn = 0; jn < 4; ++jn) {
            bf16x8 wff = WFRAG(wf_b, jn, ks);
#pragma unroll
            for (int i = 0; i < 4; ++i)
                af[i][jn] = __builtin_amdgcn_mfma_f32_16x16x32_bf16(hf[i], wff, af[i][jn], 0, 0, 0);
        }
    }
    {
        float bias[4];
#pragma unroll
        for (int jn = 0; jn < 4; ++jn) bias[jn] = bff[w * 64 + jn * 16 + lc];
        float* outn = out + (size_t)node * 16384;
#pragma unroll
        for (int i = 0; i < 4; ++i)
#pragma unroll
            for (int jn = 0; jn < 4; ++jn)
#pragma unroll
                for (int r = 0; r < 4; ++r) {
                    int row = i * 16 + quad * 4 + r;
                    int col = w * 64 + jn * 16 + lc;
                    float v = af[i][jn][r] + bias[jn];
                    v = fmaxf(v, 0.0f);
                    v += b2f(lds_h[row * 264 + col]);
                    outn[row * 256 + col] = v;
                }
    }
#undef WFRAG
#undef HFRAG
}

extern "C" void kernel_launch(void* const* d_in, const int* in_sizes, int n_in,
                              void* d_out, int out_size, void* d_ws, size_t ws_size,
                              hipStream_t stream) {
    const float* x   = (const float*)d_in[0];
    const float* pos = (const float*)d_in[1];
    const float* Wq  = (const float*)d_in[2];
    const float* Wk  = (const float*)d_in[3];
    const float* Wv  = (const float*)d_in[4];
    const float* Wf  = (const float*)d_in[5];
    const float* bff = (const float*)d_in[6];
    unsigned short* wsw = (unsigned short*)d_ws;   // 4 x 65536 bf16 = 512 KB
    float* o = (float*)d_out;

    hipLaunchKernelGGL(swizzle_w_kernel, dim3(128), dim3(256), 0, stream, Wq, Wk, Wv, Wf, wsw);
    hipLaunchKernelGGL(fused_node_kernel, dim3(4096), dim3(256), 0, stream, x, pos, wsw, bff, o);
}

// Round 3
// 707.536 us; speedup vs baseline: 2.6504x; 1.9682x over previous
//
#include <hip/hip_runtime.h>

// Fused TemporalAttentionLayer for MI355X (gfx950), round 5.
// N=4096 nodes, T=64, D=256, H=16, dh=16. One node per block, 4 waves.
// Wave w owns output columns [64w, 64w+64) == heads 4w..4w+3.
//
// Round-5: make 3 blocks/CU actually fit (rounds 3/4 spilled 4-6 GB):
//  - Per-head QK-pass THEN V-pass (split ks-loops): peak accum regs 48->32,
//    weight streams 3->2 per loop. True peak ~90 regs << 168 budget.
//  - sched_barrier(0) between heads: stops the scheduler hoisting the next
//    head's weight loads across the straight-line unrolled body (the actual
//    cause of round-4's spills at VGPR budget 168).
//  - Native __bf16 casts -> compiler emits v_cvt_pk_bf16_f32 (3 VALU ops ->
//    0.5 per conversion; ~480 conversions/wave). Rounding identical (RNE).
//  - Causal tile skip kept: 20 instead of 32 attention MFMAs per head.

typedef __attribute__((ext_vector_type(4))) float f32x4;
typedef __attribute__((ext_vector_type(8))) short bf16x8;
typedef __attribute__((ext_vector_type(4))) short bf16x4;

__device__ __forceinline__ short f2bs(float f) {
    union { __bf16 b; short s; } u;
    u.b = (__bf16)f;                 // RNE, lowered to v_cvt_pk_bf16_f32 pairs
    return u.s;
}
__device__ __forceinline__ float b2f(unsigned short s) {
    union { unsigned u; float f; } v; v.u = ((unsigned)s) << 16; return v.f;
}

// ---- preprocess: cast fp32 weights [K=256][N=256] to bf16 in MFMA frag order.
// Layout: [ntile(16)][kstep(8)][lane(64)][j(8)],
// element = W[ks*32+(lane>>4)*8+j][nt*16+(lane&15)].
// Serves as B-frag of W (straight GEMM) AND A-frag of W^T (transposed GEMM).
__global__ void swizzle_w_kernel(const float* __restrict__ Wq,
                                 const float* __restrict__ Wk,
                                 const float* __restrict__ Wv,
                                 const float* __restrict__ Wf,
                                 unsigned short* __restrict__ ws) {
    int tid  = blockIdx.x * 256 + threadIdx.x;   // 0..32767
    int mat  = tid >> 13;
    int rem  = tid & 8191;
    int nt   = rem >> 9;
    int ks   = (rem >> 6) & 7;
    int lane = rem & 63;
    const float* W = (mat == 0) ? Wq : (mat == 1) ? Wk : (mat == 2) ? Wv : Wf;
    int n  = nt * 16 + (lane & 15);
    int k0 = ks * 32 + (lane >> 4) * 8;
    bf16x8 o;
#pragma unroll
    for (int j = 0; j < 8; ++j) o[j] = f2bs(W[(k0 + j) * 256 + n]);
    *(bf16x8*)(ws + (size_t)mat * 65536 + (size_t)rem * 8) = o;
}

__global__ __launch_bounds__(256, 3) void fused_node_kernel(
    const float* __restrict__ x, const float* __restrict__ pos,
    const unsigned short* __restrict__ wsw, const float* __restrict__ bff,
    float* __restrict__ out)
{
    __shared__ unsigned short lds_h[64 * 264];   // h, later attn_out (bf16, pad 8)

    const int tid  = threadIdx.x;
    const int w    = tid >> 6;
    const int lane = tid & 63;
    const int quad = lane >> 4;
    const int lc   = lane & 15;
    const int node = blockIdx.x;

    // ---- stage 1: h = x + pos_emb  -> bf16 LDS
    {
        const float4* xv = (const float4*)(x + (size_t)node * 16384);
        const float4* pv = (const float4*)pos;
#pragma unroll
        for (int it = 0; it < 16; ++it) {
            int idx = it * 256 + tid;           // 4096 float4 chunks
            float4 a = xv[idx];
            float4 b = pv[idx];
            int row = idx >> 6, c4 = idx & 63;
            ushort4 o;
            o.x = (unsigned short)f2bs(a.x + b.x);
            o.y = (unsigned short)f2bs(a.y + b.y);
            o.z = (unsigned short)f2bs(a.z + b.z);
            o.w = (unsigned short)f2bs(a.w + b.w);
            *(ushort4*)&lds_h[row * 264 + c4 * 4] = o;
        }
    }
    __syncthreads();

    const f32x4 fzero = {0.f, 0.f, 0.f, 0.f};

    // fragment base pointers for this wave (ntile chunk = w*4 .. w*4+3)
    const unsigned short* wq_b = wsw;
    const unsigned short* wk_b = wsw + 65536;
    const unsigned short* wv_b = wsw + 131072;
    const unsigned short* wf_b = wsw + 196608;
#define WFRAG(base, mt, ks) (*(const bf16x8*)((base) + (size_t)(((w * 4 + (mt)) * 8 + (ks)) * 64 + lane) * 8))
#define HFRAG(j, ks) (*(const bf16x8*)&lds_h[(16 * (j) + lc) * 264 + (ks) * 32 + quad * 8])

    // exp(s*0.125) == exp2(s * 0.125*log2(e))
    const float SC = 0.18033688011112042f;

    bf16x4 o_pk[4][4];   // packed attn_out [head][ttile]; all indices static

#pragma unroll
    for (int h = 0; h < 4; ++h) {
        // fence: no hoisting of this head's (or later heads') loads into the
        // previous head's body — keeps scheduler pressure inside the budget
        __builtin_amdgcn_sched_barrier(0);

        // ---- QK pass for head (4w+h):
        // aq[j]: lane holds Q[t=16j+lc][dh=4quad+r]   (score B frag)
        // ak[j]: lane holds K[t=16j+lc][dh=4quad+r]   (score A frag)
        f32x4 aq[4], ak[4];
#pragma unroll
        for (int j = 0; j < 4; ++j) { aq[j] = fzero; ak[j] = fzero; }
#pragma unroll
        for (int ks = 0; ks < 8; ++ks) {
            bf16x8 hf[4];
#pragma unroll
            for (int j = 0; j < 4; ++j) hf[j] = HFRAG(j, ks);
            bf16x8 wfq = WFRAG(wq_b, h, ks);
            bf16x8 wfk = WFRAG(wk_b, h, ks);
#pragma unroll
            for (int j = 0; j < 4; ++j) {
                aq[j] = __builtin_amdgcn_mfma_f32_16x16x32_bf16(wfq, hf[j], aq[j], 0, 0, 0);
                ak[j] = __builtin_amdgcn_mfma_f32_16x16x32_bf16(wfk, hf[j], ak[j], 0, 0, 0);
            }
        }
        bf16x4 qf[4], kf[4];
#pragma unroll
        for (int j = 0; j < 4; ++j)
#pragma unroll
            for (int r = 0; r < 4; ++r) {
                qf[j][r] = f2bs(aq[j][r]);
                kf[j][r] = f2bs(ak[j][r]);
            }

        // ---- V pass: av[i]: lane holds V[s=16i+4quad+r][dh=lc] (PV B frag)
        f32x4 av[4];
#pragma unroll
        for (int i = 0; i < 4; ++i) av[i] = fzero;
#pragma unroll
        for (int ks = 0; ks < 8; ++ks) {
            bf16x8 hf[4];
#pragma unroll
            for (int i = 0; i < 4; ++i) hf[i] = HFRAG(i, ks);
            bf16x8 wfv = WFRAG(wv_b, h, ks);
#pragma unroll
            for (int i = 0; i < 4; ++i)
                av[i] = __builtin_amdgcn_mfma_f32_16x16x32_bf16(hf[i], wfv, av[i], 0, 0, 0);
        }
        bf16x4 vf[4];
#pragma unroll
        for (int i = 0; i < 4; ++i)
#pragma unroll
            for (int r = 0; r < 4; ++r) vf[i][r] = f2bs(av[i][r]);

        // ---- attention, row-block (ttile) at a time, causal tile skip
#pragma unroll
        for (int i = 0; i < 4; ++i) {
            f32x4 st[4];   // only st[0..i] used
#pragma unroll
            for (int js = 0; js <= i; ++js)
                st[js] = __builtin_amdgcn_mfma_f32_16x16x16bf16_1k(kf[js], qf[i], fzero, 0, 0, 0);
            // lane holds S[t=16i+lc][s=16js+4quad+r]
            float sum = 0.f;
#pragma unroll
            for (int js = 0; js <= i; ++js)
#pragma unroll
                for (int r = 0; r < 4; ++r) {
                    float p = __builtin_amdgcn_exp2f(st[js][r] * SC);
                    if (js == i) p = (4 * quad + r <= lc) ? p : 0.0f;
                    st[js][r] = p;
                    sum += p;
                }
            sum += __shfl_xor(sum, 16, 64);
            sum += __shfl_xor(sum, 32, 64);
            float rinv = __builtin_amdgcn_rcpf(sum);

            f32x4 O = fzero;
#pragma unroll
            for (int js = 0; js <= i; ++js) {
                bf16x4 pa;
#pragma unroll
                for (int r = 0; r < 4; ++r) pa[r] = f2bs(st[js][r] * rinv);
                O = __builtin_amdgcn_mfma_f32_16x16x16bf16_1k(pa, vf[js], O, 0, 0, 0);
            }
            // O lane holds attn_out[t=16i+4quad+r][dh=lc]
#pragma unroll
            for (int r = 0; r < 4; ++r) o_pk[h][i][r] = f2bs(O[r]);
        }
    }
    __builtin_amdgcn_sched_barrier(0);

    __syncthreads();   // all lds_h (h) reads done; it now becomes attn_out

#pragma unroll
    for (int h = 0; h < 4; ++h)
#pragma unroll
        for (int i = 0; i < 4; ++i)
#pragma unroll
            for (int r = 0; r < 4; ++r)
                lds_h[(16 * i + 4 * quad + r) * 264 + w * 64 + h * 16 + lc] =
                    (unsigned short)o_pk[h][i][r];

    __syncthreads();   // attn_out complete across waves

    // ---- FFN (straight): af[i][jn] = attn_out @ Wff
    f32x4 af[4][4];
#pragma unroll
    for (int i = 0; i < 4; ++i)
#pragma unroll
        for (int j = 0; j < 4; ++j) af[i][j] = fzero;
#pragma unroll
    for (int ks = 0; ks < 8; ++ks) {
        bf16x8 hf[4];
#pragma unroll
        for (int i = 0; i < 4; ++i) hf[i] = HFRAG(i, ks);
#pragma unroll
        for (int jn = 0; jn < 4; ++jn) {
            bf16x8 wff = WFRAG(wf_b, jn, ks);
#pragma unroll
            for (int i = 0; i < 4; ++i)
                af[i][jn] = __builtin_amdgcn_mfma_f32_16x16x32_bf16(hf[i], wff, af[i][jn], 0, 0, 0);
        }
    }
    {
        float bias[4];
#pragma unroll
        for (int jn = 0; jn < 4; ++jn) bias[jn] = bff[w * 64 + jn * 16 + lc];
        float* outn = out + (size_t)node * 16384;
#pragma unroll
        for (int i = 0; i < 4; ++i)
#pragma unroll
            for (int jn = 0; jn < 4; ++jn)
#pragma unroll
                for (int r = 0; r < 4; ++r) {
                    int row = i * 16 + quad * 4 + r;
                    int col = w * 64 + jn * 16 + lc;
                    float v = af[i][jn][r] + bias[jn];
                    v = fmaxf(v, 0.0f);
                    v += b2f(lds_h[row * 264 + col]);
                    outn[row * 256 + col] = v;
                }
    }
#undef WFRAG
#undef HFRAG
}

extern "C" void kernel_launch(void* const* d_in, const int* in_sizes, int n_in,
                              void* d_out, int out_size, void* d_ws, size_t ws_size,
                              hipStream_t stream) {
    const float* x   = (const float*)d_in[0];
    const float* pos = (const float*)d_in[1];
    const float* Wq  = (const float*)d_in[2];
    const float* Wk  = (const float*)d_in[3];
    const float* Wv  = (const float*)d_in[4];
    const float* Wf  = (const float*)d_in[5];
    const float* bff = (const float*)d_in[6];
    unsigned short* wsw = (unsigned short*)d_ws;   // 4 x 65536 bf16 = 512 KB
    float* o = (float*)d_out;

    hipLaunchKernelGGL(swizzle_w_kernel, dim3(128), dim3(256), 0, stream, Wq, Wk, Wv, Wf, wsw);
    hipLaunchKernelGGL(fused_node_kernel, dim3(4096), dim3(256), 0, stream, x, pos, wsw, bff, o);
}

// Round 4
// 595.122 us; speedup vs baseline: 3.1510x; 1.1889x over previous
//
#include <hip/hip_runtime.h>

// Fused TemporalAttentionLayer for MI355X (gfx950), round 6.
// N=4096 nodes, T=64, D=256, H=16, dh=16. One node per block.
//
// Round-6: occupancy via BLOCK SHAPE, not register-budget squeezing.
//  512 threads / 8 waves per block; wave w owns heads {2w, 2w+1} = output
//  cols [32w, 32w+32). Per-wave register demand drops by construction:
//   - 2 heads' packed QKV frags = 48 regs (was 96)
//   - NO o_pk register file: attention outputs write directly to LDS
//     (mid-kernel sync retires lds_h's h-role first)
//   - split QK-pass / V-pass keeps accum peak at 32
//  Peak ~100 total regs < 128 budget of __launch_bounds__(512,4)
//  -> 2 blocks x 8 waves = 16 waves/CU (50%), double round-2's 8,
//  with zero spill risk margin (rounds 3-5 all died on spills).
//
//  Kept from rounds 3-5: causal tile skip (20 vs 32 attn MFMAs/head),
//  exp2+rcp softmax, native __bf16 casts (v_cvt_pk_bf16_f32).
//  Phases: stage -> sync -> QKV(h0,h1) -> sync -> attn(h0,h1)->LDS
//          -> sync -> FFN+residual -> store.

typedef __attribute__((ext_vector_type(4))) float f32x4;
typedef __attribute__((ext_vector_type(8))) short bf16x8;
typedef __attribute__((ext_vector_type(4))) short bf16x4;

__device__ __forceinline__ short f2bs(float f) {
    union { __bf16 b; short s; } u;
    u.b = (__bf16)f;                 // RNE, lowered to v_cvt_pk_bf16_f32 pairs
    return u.s;
}
__device__ __forceinline__ float b2f(unsigned short s) {
    union { unsigned u; float f; } v; v.u = ((unsigned)s) << 16; return v.f;
}

// ---- preprocess: cast fp32 weights [K=256][N=256] to bf16 in MFMA frag order.
// Layout: [ntile(16)][kstep(8)][lane(64)][j(8)],
// element = W[ks*32+(lane>>4)*8+j][nt*16+(lane&15)].
// Serves as B-frag of W (straight GEMM) AND A-frag of W^T (transposed GEMM).
__global__ void swizzle_w_kernel(const float* __restrict__ Wq,
                                 const float* __restrict__ Wk,
                                 const float* __restrict__ Wv,
                                 const float* __restrict__ Wf,
                                 unsigned short* __restrict__ ws) {
    int tid  = blockIdx.x * 256 + threadIdx.x;   // 0..32767
    int mat  = tid >> 13;
    int rem  = tid & 8191;
    int nt   = rem >> 9;
    int ks   = (rem >> 6) & 7;
    int lane = rem & 63;
    const float* W = (mat == 0) ? Wq : (mat == 1) ? Wk : (mat == 2) ? Wv : Wf;
    int n  = nt * 16 + (lane & 15);
    int k0 = ks * 32 + (lane >> 4) * 8;
    bf16x8 o;
#pragma unroll
    for (int j = 0; j < 8; ++j) o[j] = f2bs(W[(k0 + j) * 256 + n]);
    *(bf16x8*)(ws + (size_t)mat * 65536 + (size_t)rem * 8) = o;
}

__global__ __launch_bounds__(512, 4) void fused_node_kernel(
    const float* __restrict__ x, const float* __restrict__ pos,
    const unsigned short* __restrict__ wsw, const float* __restrict__ bff,
    float* __restrict__ out)
{
    __shared__ unsigned short lds_h[64 * 264];   // h, later attn_out (bf16, pad 8)

    const int tid  = threadIdx.x;
    const int w    = tid >> 6;        // wave 0..7, owns heads 2w, 2w+1
    const int lane = tid & 63;
    const int quad = lane >> 4;
    const int lc   = lane & 15;
    const int node = blockIdx.x;

    // ---- stage 1: h = x + pos_emb  -> bf16 LDS
    {
        const float4* xv = (const float4*)(x + (size_t)node * 16384);
        const float4* pv = (const float4*)pos;
#pragma unroll
        for (int it = 0; it < 8; ++it) {
            int idx = it * 512 + tid;           // 4096 float4 chunks
            float4 a = xv[idx];
            float4 b = pv[idx];
            int row = idx >> 6, c4 = idx & 63;
            ushort4 o;
            o.x = (unsigned short)f2bs(a.x + b.x);
            o.y = (unsigned short)f2bs(a.y + b.y);
            o.z = (unsigned short)f2bs(a.z + b.z);
            o.w = (unsigned short)f2bs(a.w + b.w);
            *(ushort4*)&lds_h[row * 264 + c4 * 4] = o;
        }
    }
    __syncthreads();

    const f32x4 fzero = {0.f, 0.f, 0.f, 0.f};

    // fragment base pointers; this wave's ntile chunk = {2w, 2w+1}
    const unsigned short* wq_b = wsw;
    const unsigned short* wk_b = wsw + 65536;
    const unsigned short* wv_b = wsw + 131072;
    const unsigned short* wf_b = wsw + 196608;
#define WFRAG(base, mt, ks) (*(const bf16x8*)((base) + (size_t)(((w * 2 + (mt)) * 8 + (ks)) * 64 + lane) * 8))
#define HFRAG(j, ks) (*(const bf16x8*)&lds_h[(16 * (j) + lc) * 264 + (ks) * 32 + quad * 8])

    // exp(s*0.125) == exp2(s * 0.125*log2(e))
    const float SC = 0.18033688011112042f;

    bf16x4 qf[2][4], kf[2][4], vf[2][4];   // packed per-head frags, static idx

#pragma unroll
    for (int h = 0; h < 2; ++h) {
        __builtin_amdgcn_sched_barrier(0);   // no cross-head load hoisting

        // ---- QK pass for head (2w+h):
        // aq[j]: lane holds Q[t=16j+lc][dh=4quad+r]   (score B frag)
        // ak[j]: lane holds K[t=16j+lc][dh=4quad+r]   (score A frag)
        f32x4 aq[4], ak[4];
#pragma unroll
        for (int j = 0; j < 4; ++j) { aq[j] = fzero; ak[j] = fzero; }
#pragma unroll
        for (int ks = 0; ks < 8; ++ks) {
            bf16x8 hf[4];
#pragma unroll
            for (int j = 0; j < 4; ++j) hf[j] = HFRAG(j, ks);
            bf16x8 wfq = WFRAG(wq_b, h, ks);
            bf16x8 wfk = WFRAG(wk_b, h, ks);
#pragma unroll
            for (int j = 0; j < 4; ++j) {
                aq[j] = __builtin_amdgcn_mfma_f32_16x16x32_bf16(wfq, hf[j], aq[j], 0, 0, 0);
                ak[j] = __builtin_amdgcn_mfma_f32_16x16x32_bf16(wfk, hf[j], ak[j], 0, 0, 0);
            }
        }
#pragma unroll
        for (int j = 0; j < 4; ++j)
#pragma unroll
            for (int r = 0; r < 4; ++r) {
                qf[h][j][r] = f2bs(aq[j][r]);
                kf[h][j][r] = f2bs(ak[j][r]);
            }

        // ---- V pass: av[i]: lane holds V[s=16i+4quad+r][dh=lc] (PV B frag)
        f32x4 av[4];
#pragma unroll
        for (int i = 0; i < 4; ++i) av[i] = fzero;
#pragma unroll
        for (int ks = 0; ks < 8; ++ks) {
            bf16x8 hf[4];
#pragma unroll
            for (int i = 0; i < 4; ++i) hf[i] = HFRAG(i, ks);
            bf16x8 wfv = WFRAG(wv_b, h, ks);
#pragma unroll
            for (int i = 0; i < 4; ++i)
                av[i] = __builtin_amdgcn_mfma_f32_16x16x32_bf16(hf[i], wfv, av[i], 0, 0, 0);
        }
#pragma unroll
        for (int i = 0; i < 4; ++i)
#pragma unroll
            for (int r = 0; r < 4; ++r) vf[h][i][r] = f2bs(av[i][r]);
    }
    __builtin_amdgcn_sched_barrier(0);

    __syncthreads();   // ALL waves done reading h; lds_h becomes attn_out

    // ---- attention per head, outputs straight to LDS (no o_pk regs)
#pragma unroll
    for (int h = 0; h < 2; ++h) {
        __builtin_amdgcn_sched_barrier(0);
#pragma unroll
        for (int i = 0; i < 4; ++i) {
            f32x4 st[4];   // only st[0..i] used (causal tile skip)
#pragma unroll
            for (int js = 0; js <= i; ++js)
                st[js] = __builtin_amdgcn_mfma_f32_16x16x16bf16_1k(kf[h][js], qf[h][i], fzero, 0, 0, 0);
            // lane holds S[t=16i+lc][s=16js+4quad+r]
            float sum = 0.f;
#pragma unroll
            for (int js = 0; js <= i; ++js)
#pragma unroll
                for (int r = 0; r < 4; ++r) {
                    float p = __builtin_amdgcn_exp2f(st[js][r] * SC);
                    if (js == i) p = (4 * quad + r <= lc) ? p : 0.0f;
                    st[js][r] = p;
                    sum += p;
                }
            sum += __shfl_xor(sum, 16, 64);
            sum += __shfl_xor(sum, 32, 64);
            float rinv = __builtin_amdgcn_rcpf(sum);

            f32x4 O = fzero;
#pragma unroll
            for (int js = 0; js <= i; ++js) {
                bf16x4 pa;
#pragma unroll
                for (int r = 0; r < 4; ++r) pa[r] = f2bs(st[js][r] * rinv);
                O = __builtin_amdgcn_mfma_f32_16x16x16bf16_1k(pa, vf[h][js], O, 0, 0, 0);
            }
            // O lane holds attn_out[t=16i+4quad+r][dh=lc]; col = (2w+h)*16+lc
#pragma unroll
            for (int r = 0; r < 4; ++r)
                lds_h[(16 * i + 4 * quad + r) * 264 + w * 32 + h * 16 + lc] =
                    (unsigned short)f2bs(O[r]);
        }
    }

    __syncthreads();   // attn_out complete across waves

    // ---- FFN (straight): af[i][jn] = attn_out @ Wff ; wave owns 32 cols
    f32x4 af[4][2];
#pragma unroll
    for (int i = 0; i < 4; ++i)
#pragma unroll
        for (int j = 0; j < 2; ++j) af[i][j] = fzero;
#pragma unroll
    for (int ks = 0; ks < 8; ++ks) {
        bf16x8 hf[4];
#pragma unroll
        for (int i = 0; i < 4; ++i) hf[i] = HFRAG(i, ks);
#pragma unroll
        for (int jn = 0; jn < 2; ++jn) {
            bf16x8 wff = WFRAG(wf_b, jn, ks);
#pragma unroll
            for (int i = 0; i < 4; ++i)
                af[i][jn] = __builtin_amdgcn_mfma_f32_16x16x32_bf16(hf[i], wff, af[i][jn], 0, 0, 0);
        }
    }
    {
        float bias[2];
#pragma unroll
        for (int jn = 0; jn < 2; ++jn) bias[jn] = bff[w * 32 + jn * 16 + lc];
        float* outn = out + (size_t)node * 16384;
#pragma unroll
        for (int i = 0; i < 4; ++i)
#pragma unroll
            for (int jn = 0; jn < 2; ++jn)
#pragma unroll
                for (int r = 0; r < 4; ++r) {
                    int row = i * 16 + quad * 4 + r;
                    int col = w * 32 + jn * 16 + lc;
                    float v = af[i][jn][r] + bias[jn];
                    v = fmaxf(v, 0.0f);
                    v += b2f(lds_h[row * 264 + col]);
                    outn[row * 256 + col] = v;
                }
    }
#undef WFRAG
#undef HFRAG
}

extern "C" void kernel_launch(void* const* d_in, const int* in_sizes, int n_in,
                              void* d_out, int out_size, void* d_ws, size_t ws_size,
                              hipStream_t stream) {
    const float* x   = (const float*)d_in[0];
    const float* pos = (const float*)d_in[1];
    const float* Wq  = (const float*)d_in[2];
    const float* Wk  = (const float*)d_in[3];
    const float* Wv  = (const float*)d_in[4];
    const float* Wf  = (const float*)d_in[5];
    const float* bff = (const float*)d_in[6];
    unsigned short* wsw = (unsigned short*)d_ws;   // 4 x 65536 bf16 = 512 KB
    float* o = (float*)d_out;

    hipLaunchKernelGGL(swizzle_w_kernel, dim3(128), dim3(256), 0, stream, Wq, Wk, Wv, Wf, wsw);
    hipLaunchKernelGGL(fused_node_kernel, dim3(4096), dim3(512), 0, stream, x, pos, wsw, bff, o);
}

// Round 5
// 541.747 us; speedup vs baseline: 3.4615x; 1.0985x over previous
//
#include <hip/hip_runtime.h>

// Fused TemporalAttentionLayer for MI355X (gfx950), round 7.
// N=4096 nodes, T=64, D=256, H=16, dh=16. One node per block.
// 512 threads / 8 waves; wave w owns heads {2w, 2w+1} = out cols [32w,32w+32).
//
// Round-7: cut barrier serialization + LDS traffic (round 6 showed latency
// regime: MfmaUtil 23 / VALU 27 / HBM 35 / occ 42, nothing saturated).
//  - SEPARATE attn_out LDS buffer (67.6 KB/block total, still 2 blocks/CU):
//    removes the h-dead barrier. Phases: stage -> sync -> {QKV+attn+O-write,
//    per wave, no syncs} -> sync -> FFN.  2 barriers (was 3).
//  - QKV re-fused into ONE ks-loop per head (safe now: nothing held across
//    heads; peak ~95 regs < 128 budget of (512,4)). HFRAG reads 160->96 per
//    wave, with matching cut in LDS bank-conflict tax and address VALU.
//  - Kept: causal tile skip, exp2+rcp softmax, native __bf16 casts,
//    sched_barrier(0) between heads (no cross-head load hoisting).

typedef __attribute__((ext_vector_type(4))) float f32x4;
typedef __attribute__((ext_vector_type(8))) short bf16x8;
typedef __attribute__((ext_vector_type(4))) short bf16x4;

__device__ __forceinline__ short f2bs(float f) {
    union { __bf16 b; short s; } u;
    u.b = (__bf16)f;                 // RNE, lowered to v_cvt_pk_bf16_f32 pairs
    return u.s;
}
__device__ __forceinline__ float b2f(unsigned short s) {
    union { unsigned u; float f; } v; v.u = ((unsigned)s) << 16; return v.f;
}

// ---- preprocess: cast fp32 weights [K=256][N=256] to bf16 in MFMA frag order.
// Layout: [ntile(16)][kstep(8)][lane(64)][j(8)],
// element = W[ks*32+(lane>>4)*8+j][nt*16+(lane&15)].
// Serves as B-frag of W (straight GEMM) AND A-frag of W^T (transposed GEMM).
__global__ void swizzle_w_kernel(const float* __restrict__ Wq,
                                 const float* __restrict__ Wk,
                                 const float* __restrict__ Wv,
                                 const float* __restrict__ Wf,
                                 unsigned short* __restrict__ ws) {
    int tid  = blockIdx.x * 256 + threadIdx.x;   // 0..32767
    int mat  = tid >> 13;
    int rem  = tid & 8191;
    int nt   = rem >> 9;
    int ks   = (rem >> 6) & 7;
    int lane = rem & 63;
    const float* W = (mat == 0) ? Wq : (mat == 1) ? Wk : (mat == 2) ? Wv : Wf;
    int n  = nt * 16 + (lane & 15);
    int k0 = ks * 32 + (lane >> 4) * 8;
    bf16x8 o;
#pragma unroll
    for (int j = 0; j < 8; ++j) o[j] = f2bs(W[(k0 + j) * 256 + n]);
    *(bf16x8*)(ws + (size_t)mat * 65536 + (size_t)rem * 8) = o;
}

__global__ __launch_bounds__(512, 4) void fused_node_kernel(
    const float* __restrict__ x, const float* __restrict__ pos,
    const unsigned short* __restrict__ wsw, const float* __restrict__ bff,
    float* __restrict__ out)
{
    __shared__ unsigned short lds_h[64 * 264];   // h (bf16, pad 8)
    __shared__ unsigned short lds_o[64 * 264];   // attn_out (bf16, pad 8)

    const int tid  = threadIdx.x;
    const int w    = tid >> 6;        // wave 0..7, owns heads 2w, 2w+1
    const int lane = tid & 63;
    const int quad = lane >> 4;
    const int lc   = lane & 15;
    const int node = blockIdx.x;

    // ---- stage 1: h = x + pos_emb  -> bf16 LDS
    {
        const float4* xv = (const float4*)(x + (size_t)node * 16384);
        const float4* pv = (const float4*)pos;
#pragma unroll
        for (int it = 0; it < 8; ++it) {
            int idx = it * 512 + tid;           // 4096 float4 chunks
            float4 a = xv[idx];
            float4 b = pv[idx];
            int row = idx >> 6, c4 = idx & 63;
            ushort4 o;
            o.x = (unsigned short)f2bs(a.x + b.x);
            o.y = (unsigned short)f2bs(a.y + b.y);
            o.z = (unsigned short)f2bs(a.z + b.z);
            o.w = (unsigned short)f2bs(a.w + b.w);
            *(ushort4*)&lds_h[row * 264 + c4 * 4] = o;
        }
    }
    __syncthreads();

    const f32x4 fzero = {0.f, 0.f, 0.f, 0.f};

    // fragment base pointers; this wave's ntile chunk = {2w, 2w+1}
    const unsigned short* wq_b = wsw;
    const unsigned short* wk_b = wsw + 65536;
    const unsigned short* wv_b = wsw + 131072;
    const unsigned short* wf_b = wsw + 196608;
#define WFRAG(base, mt, ks) (*(const bf16x8*)((base) + (size_t)(((w * 2 + (mt)) * 8 + (ks)) * 64 + lane) * 8))
#define HFRAG(j, ks) (*(const bf16x8*)&lds_h[(16 * (j) + lc) * 264 + (ks) * 32 + quad * 8])
#define OFRAG(j, ks) (*(const bf16x8*)&lds_o[(16 * (j) + lc) * 264 + (ks) * 32 + quad * 8])

    // exp(s*0.125) == exp2(s * 0.125*log2(e))
    const float SC = 0.18033688011112042f;

    // ---- per head: fused QKV (one ks pass), then attention, O -> lds_o.
    // No barriers inside: h is read-only, lds_o regions are per-wave-owned.
#pragma unroll
    for (int h = 0; h < 2; ++h) {
        __builtin_amdgcn_sched_barrier(0);   // no cross-head load hoisting

        // aq[j]: lane holds Q[t=16j+lc][dh=4quad+r]   (score B frag)
        // ak[j]: lane holds K[t=16j+lc][dh=4quad+r]   (score A frag)
        // av[i]: lane holds V[s=16i+4quad+r][dh=lc]   (PV B frag)
        f32x4 aq[4], ak[4], av[4];
#pragma unroll
        for (int j = 0; j < 4; ++j) { aq[j] = fzero; ak[j] = fzero; av[j] = fzero; }
#pragma unroll
        for (int ks = 0; ks < 8; ++ks) {
            bf16x8 hf[4];
#pragma unroll
            for (int j = 0; j < 4; ++j) hf[j] = HFRAG(j, ks);
            bf16x8 wfq = WFRAG(wq_b, h, ks);
            bf16x8 wfk = WFRAG(wk_b, h, ks);
            bf16x8 wfv = WFRAG(wv_b, h, ks);
#pragma unroll
            for (int j = 0; j < 4; ++j) {
                aq[j] = __builtin_amdgcn_mfma_f32_16x16x32_bf16(wfq, hf[j], aq[j], 0, 0, 0);
                ak[j] = __builtin_amdgcn_mfma_f32_16x16x32_bf16(wfk, hf[j], ak[j], 0, 0, 0);
                av[j] = __builtin_amdgcn_mfma_f32_16x16x32_bf16(hf[j], wfv, av[j], 0, 0, 0);
            }
        }
        bf16x4 qf[4], kf[4], vf[4];
#pragma unroll
        for (int j = 0; j < 4; ++j)
#pragma unroll
            for (int r = 0; r < 4; ++r) {
                qf[j][r] = f2bs(aq[j][r]);
                kf[j][r] = f2bs(ak[j][r]);
                vf[j][r] = f2bs(av[j][r]);
            }

        // ---- attention, row-block (ttile) at a time, causal tile skip
#pragma unroll
        for (int i = 0; i < 4; ++i) {
            f32x4 st[4];   // only st[0..i] used
#pragma unroll
            for (int js = 0; js <= i; ++js)
                st[js] = __builtin_amdgcn_mfma_f32_16x16x16bf16_1k(kf[js], qf[i], fzero, 0, 0, 0);
            // lane holds S[t=16i+lc][s=16js+4quad+r]
            float sum = 0.f;
#pragma unroll
            for (int js = 0; js <= i; ++js)
#pragma unroll
                for (int r = 0; r < 4; ++r) {
                    float p = __builtin_amdgcn_exp2f(st[js][r] * SC);
                    if (js == i) p = (4 * quad + r <= lc) ? p : 0.0f;
                    st[js][r] = p;
                    sum += p;
                }
            sum += __shfl_xor(sum, 16, 64);
            sum += __shfl_xor(sum, 32, 64);
            float rinv = __builtin_amdgcn_rcpf(sum);

            f32x4 O = fzero;
#pragma unroll
            for (int js = 0; js <= i; ++js) {
                bf16x4 pa;
#pragma unroll
                for (int r = 0; r < 4; ++r) pa[r] = f2bs(st[js][r] * rinv);
                O = __builtin_amdgcn_mfma_f32_16x16x16bf16_1k(pa, vf[js], O, 0, 0, 0);
            }
            // O lane holds attn_out[t=16i+4quad+r][dh=lc]; col = (2w+h)*16+lc
#pragma unroll
            for (int r = 0; r < 4; ++r)
                lds_o[(16 * i + 4 * quad + r) * 264 + w * 32 + h * 16 + lc] =
                    (unsigned short)f2bs(O[r]);
        }
    }

    __syncthreads();   // attn_out complete across waves

    // ---- FFN (straight): af[i][jn] = attn_out @ Wff ; wave owns 32 cols
    f32x4 af[4][2];
#pragma unroll
    for (int i = 0; i < 4; ++i)
#pragma unroll
        for (int j = 0; j < 2; ++j) af[i][j] = fzero;
#pragma unroll
    for (int ks = 0; ks < 8; ++ks) {
        bf16x8 hf[4];
#pragma unroll
        for (int i = 0; i < 4; ++i) hf[i] = OFRAG(i, ks);
#pragma unroll
        for (int jn = 0; jn < 2; ++jn) {
            bf16x8 wff = WFRAG(wf_b, jn, ks);
#pragma unroll
            for (int i = 0; i < 4; ++i)
                af[i][jn] = __builtin_amdgcn_mfma_f32_16x16x32_bf16(hf[i], wff, af[i][jn], 0, 0, 0);
        }
    }
    {
        float bias[2];
#pragma unroll
        for (int jn = 0; jn < 2; ++jn) bias[jn] = bff[w * 32 + jn * 16 + lc];
        float* outn = out + (size_t)node * 16384;
#pragma unroll
        for (int i = 0; i < 4; ++i)
#pragma unroll
            for (int jn = 0; jn < 2; ++jn)
#pragma unroll
                for (int r = 0; r < 4; ++r) {
                    int row = i * 16 + quad * 4 + r;
                    int col = w * 32 + jn * 16 + lc;
                    float v = af[i][jn][r] + bias[jn];
                    v = fmaxf(v, 0.0f);
                    v += b2f(lds_o[row * 264 + col]);
                    outn[row * 256 + col] = v;
                }
    }
#undef WFRAG
#undef HFRAG
#undef OFRAG
}

extern "C" void kernel_launch(void* const* d_in, const int* in_sizes, int n_in,
                              void* d_out, int out_size, void* d_ws, size_t ws_size,
                              hipStream_t stream) {
    const float* x   = (const float*)d_in[0];
    const float* pos = (const float*)d_in[1];
    const float* Wq  = (const float*)d_in[2];
    const float* Wk  = (const float*)d_in[3];
    const float* Wv  = (const float*)d_in[4];
    const float* Wf  = (const float*)d_in[5];
    const float* bff = (const float*)d_in[6];
    unsigned short* wsw = (unsigned short*)d_ws;   // 4 x 65536 bf16 = 512 KB
    float* o = (float*)d_out;

    hipLaunchKernelGGL(swizzle_w_kernel, dim3(128), dim3(256), 0, stream, Wq, Wk, Wv, Wf, wsw);
    hipLaunchKernelGGL(fused_node_kernel, dim3(4096), dim3(512), 0, stream, x, pos, wsw, bff, o);
}